// Round 7
// baseline (655.716 us; speedup 1.0000x reference)
//
#include <hip/hip_runtime.h>
#include <hip/hip_fp16.h>

// ---------------------------------------------------------------------------
// 2-layer GCN (PyG GCNConv): deg^{-1/2} sym norm with self-loops.
// Round 7: column-sliced XCD-resident gathers.
//   xhT[q][N][16] fp16  (q = col-slice; 3.2 MB/slice -> fits one XCD's 4MB L2)
//   gatherT128: slice-q blocks (blockIdx&7==q -> XCD q) read ONLY slice q ->
//               random reads become L2 hits. Output aggH row-major for MFMA.
//   mgemm1: h1 = relu(aggH @ W1 + b1)            (MFMA, reg-resident B)
//   mgemm2: thT[q][N][8] = ((h1 @ W2) * dinv)    (slice-major out)
//   gatherT64 -> outT[q][N][8] fp32 (slice-major, XCD-local writes)
//   transpose+bias -> out row-major fp32
// CSR built per launch; scatter is XCD-localized (round 5).
// ---------------------------------------------------------------------------

#define NT 256

typedef _Float16 half8 __attribute__((ext_vector_type(8)));
typedef float floatx4 __attribute__((ext_vector_type(4)));

// ---------------- CSR build ----------------

__global__ void zero_counts_k(int* __restrict__ c, int n) {
    int i = blockIdx.x * NT + threadIdx.x;
    if (i < n) c[i] = 0;
}

__global__ void deg_count_k(const int* __restrict__ dst, int* __restrict__ c, int e) {
    int i = blockIdx.x * NT + threadIdx.x;
    if (i < e) atomicAdd(&c[dst[i]], 1);
}

// exclusive scan of counts -> rowptr (3-phase); also emits dinv = rsqrt(cnt+1)
__global__ void scan1_k(const int* __restrict__ counts, int* __restrict__ rowptr,
                        int* __restrict__ bsum, float* __restrict__ dinv, int n) {
    __shared__ int s[NT];
    int tid = threadIdx.x, i = blockIdx.x * NT + tid;
    int v = (i < n) ? counts[i] : 0;
    if (i < n) dinv[i] = rsqrtf((float)(v + 1));  // +1 self-loop
    s[tid] = v;
    __syncthreads();
    for (int off = 1; off < NT; off <<= 1) {
        int t = (tid >= off) ? s[tid - off] : 0;
        __syncthreads();
        if (tid >= off) s[tid] += t;
        __syncthreads();
    }
    if (i < n) rowptr[i] = s[tid] - v;  // exclusive within block
    if (tid == NT - 1) bsum[blockIdx.x] = s[tid];
}

__global__ void scan2_k(int* __restrict__ bsum, int nb) {
    __shared__ int s[512];
    __shared__ int carry;
    int tid = threadIdx.x;
    if (tid == 0) carry = 0;
    __syncthreads();
    for (int base = 0; base < nb; base += 512) {
        int i = base + tid;
        int v = (i < nb) ? bsum[i] : 0;
        s[tid] = v;
        __syncthreads();
        for (int off = 1; off < 512; off <<= 1) {
            int t = (tid >= off) ? s[tid - off] : 0;
            __syncthreads();
            if (tid >= off) s[tid] += t;
            __syncthreads();
        }
        int tot = s[511];
        if (i < nb) bsum[i] = s[tid] - v + carry;
        __syncthreads();
        if (tid == 0) carry += tot;
        __syncthreads();
    }
}

__global__ void scan3_k(int* __restrict__ rowptr, const int* __restrict__ bsum,
                        int* __restrict__ cursor, int n, int e) {
    int i = blockIdx.x * NT + threadIdx.x;
    if (i < n) {
        int r = rowptr[i] + bsum[i / NT];
        rowptr[i] = r;
        cursor[i] = r;
    } else if (i == n) {
        rowptr[n] = e;
    }
}

// XCD-localized scatter (round 5): block (blockIdx&7)==q only scatters edges
// whose dst lies in node-region q -> each srcs region written by one XCD.
__global__ __launch_bounds__(NT) void scatter_xcd_k(
    const int* __restrict__ src, const int* __restrict__ dst,
    int* __restrict__ cursor, int* __restrict__ srcs,
    int e, int rpx, int csz) {
    int q  = blockIdx.x & 7;
    int ch = blockIdx.x >> 3;
    int lo = q * rpx, hi = lo + rpx;
    int e0 = ch * csz;
    int e1 = min(e, e0 + csz);
    for (int i = e0 + (int)threadIdx.x; i < e1; i += NT) {
        int d = dst[i];
        if (d >= lo && d < hi) {
            int pos = atomicAdd(&cursor[d], 1);
            srcs[pos] = src[i];
        }
    }
}

// ---------------- conv1T: x (fp32 row-major) -> xhT[8][N][16] fp16 ----------
// thread t: node = blk*32 + (t>>3), slice q = t&7 (cols q*16..q*16+15).
// x reads fully coalesced; writes are 32B/thread, 256B-contiguous per wave
// within each slice.
__global__ void conv1T_k(const float* __restrict__ x, const float* __restrict__ dinv,
                         __half* __restrict__ xhT, int n) {
    int t = blockIdx.x * NT + threadIdx.x;
    int node = t >> 3;
    if (node >= n) return;
    int q = t & 7;
    float dn = dinv[node];
    const float4* xp = reinterpret_cast<const float4*>(x + (size_t)node * 128 + q * 16);
    __half2 h[8];
#pragma unroll
    for (int j = 0; j < 4; ++j) {
        float4 a = xp[j];
        h[2 * j + 0] = __floats2half2_rn(a.x * dn, a.y * dn);
        h[2 * j + 1] = __floats2half2_rn(a.z * dn, a.w * dn);
    }
    int4* op = reinterpret_cast<int4*>(xhT + ((size_t)q * n + node) * 16);
    op[0] = reinterpret_cast<int4*>(h)[0];
    op[1] = reinterpret_cast<int4*>(h)[1];
}

// ---------------- sliced gathers ----------------

// gatherT128: block q = blockIdx&7 handles col-slice q (16 cols) only.
// Wave = 1 node; 8 edges/iter x 8 lanes (half2 each). aggH row-major fp16.
__global__ __launch_bounds__(NT) void gatherT128_k(
    const int* __restrict__ rowptr, const int* __restrict__ srcs,
    const float* __restrict__ dinv, const __half2* __restrict__ xhT,
    __half2* __restrict__ aggH, int n) {
    int q     = blockIdx.x & 7;
    int chunk = blockIdx.x >> 3;
    int node  = chunk * 4 + (threadIdx.x >> 6);
    if (node >= n) return;
    int lane = threadIdx.x & 63;
    int g = lane >> 3;  // edge sub-slot 0..7
    int c = lane & 7;   // half2 col within slice
    const __half2* base = xhT + (size_t)q * n * 8;
    float ax = 0.f, ay = 0.f;
    int e1 = rowptr[node + 1];
    for (int e = rowptr[node]; e < e1; e += 8) {
        int idx = e + g;
        if (idx < e1) {
            float2 f = __half22float2(base[(size_t)srcs[idx] * 8 + c]);
            ax += f.x;
            ay += f.y;
        }
    }
#pragma unroll
    for (int off = 8; off < 64; off <<= 1) {
        ax += __shfl_xor(ax, off, 64);
        ay += __shfl_xor(ay, off, 64);
    }
    if (g == 0) {
        float2 s = __half22float2(base[(size_t)node * 8 + c]);  // self-loop
        float dn = dinv[node];
        aggH[(size_t)node * 64 + q * 8 + c] =
            __floats2half2_rn((ax + s.x) * dn, (ay + s.y) * dn);
    }
}

// gatherT64: slice q = 8 cols (4 half2). 16 edges/iter x 4 lanes.
// Output slice-major fp32 outT[q][N][8] (XCD-local writes, no line sharing).
__global__ __launch_bounds__(NT) void gatherT64_k(
    const int* __restrict__ rowptr, const int* __restrict__ srcs,
    const float* __restrict__ dinv, const __half2* __restrict__ thT,
    float* __restrict__ outT, int n) {
    int q     = blockIdx.x & 7;
    int chunk = blockIdx.x >> 3;
    int node  = chunk * 4 + (threadIdx.x >> 6);
    if (node >= n) return;
    int lane = threadIdx.x & 63;
    int g = lane >> 2;  // edge sub-slot 0..15
    int c = lane & 3;   // half2 col within slice
    const __half2* base = thT + (size_t)q * n * 4;
    float ax = 0.f, ay = 0.f;
    int e1 = rowptr[node + 1];
    for (int e = rowptr[node]; e < e1; e += 16) {
        int idx = e + g;
        if (idx < e1) {
            float2 f = __half22float2(base[(size_t)srcs[idx] * 4 + c]);
            ax += f.x;
            ay += f.y;
        }
    }
#pragma unroll
    for (int off = 4; off < 64; off <<= 1) {
        ax += __shfl_xor(ax, off, 64);
        ay += __shfl_xor(ay, off, 64);
    }
    if (g == 0) {
        float2 s = __half22float2(base[(size_t)node * 4 + c]);  // self-loop
        float dn = dinv[node];
        *reinterpret_cast<float2*>(&outT[((size_t)q * n + node) * 8 + c * 2]) =
            make_float2((ax + s.x) * dn, (ay + s.y) * dn);
    }
}

// transpose + bias: out[node][col] = outT[col>>3][node][col&7] + b2[col]
__global__ void tpose_bias_k(const float* __restrict__ outT,
                             const float* __restrict__ b2,
                             float* __restrict__ out, int n) {
    int idx = blockIdx.x * NT + threadIdx.x;  // one float2 each
    if (idx >= n * 32) return;
    int node = idx >> 5;
    int cp   = idx & 31;           // float2 index within row
    int q    = cp >> 2;
    int c2   = (cp & 3) * 2;       // col within slice
    float2 v = *reinterpret_cast<const float2*>(
        &outT[((size_t)q * n + node) * 8 + c2]);
    int col = q * 8 + c2;
    *reinterpret_cast<float2*>(&out[(size_t)node * 64 + col]) =
        make_float2(v.x + b2[col], v.y + b2[col + 1]);
}

// ---------------- MFMA fp16 GEMM, register-resident B ----------------
// mfma_f32_16x16x32_f16: A lane l: row=l&15, k=(l>>4)*8+j; B: col=l&15, same k;
// C/D lane l: col=l&15, row=(l>>4)*4+r. Block = 4 waves; wave w covers cols
// [w*16*NREP, (w+1)*16*NREP); block covers 64 rows.
// TOUT=false: out row-major fp16 [nrows][OC].
// TOUT=true : out slice-major fp16 [OC/8][nrows][8] (for gatherT64).
template <int OC, bool RELU, bool BIAS, bool SCALE_DINV, bool TOUT>
__global__ __launch_bounds__(NT) void mgemm_k(
    const __half* __restrict__ A, const float* __restrict__ W,
    const float* __restrict__ bias, const float* __restrict__ dinv,
    __half* __restrict__ out, int nrows) {
    constexpr int NREP = OC / 64;  // 2 for OC=128, 1 for OC=64

    const int wid  = threadIdx.x >> 6;
    const int lane = threadIdx.x & 63;
    const int lrow = lane & 15;
    const int kgrp = lane >> 4;
    const int nbase = wid * 16 * NREP;

    // B fragments (loaded once, stay in VGPRs)
    half8 bf[NREP][4];
    float bv[NREP];
#pragma unroll
    for (int nt = 0; nt < NREP; ++nt) {
        int col = nbase + nt * 16 + lrow;
#pragma unroll
        for (int kk = 0; kk < 4; ++kk) {
#pragma unroll
            for (int j = 0; j < 8; ++j) {
                int k = kk * 32 + kgrp * 8 + j;
                bf[nt][kk][j] = (_Float16)W[(size_t)k * OC + col];
            }
        }
        bv[nt] = BIAS ? bias[col] : 0.0f;
    }

    const int m0 = blockIdx.x * 64;

    floatx4 acc[4][NREP];
#pragma unroll
    for (int mt = 0; mt < 4; ++mt)
#pragma unroll
        for (int nt = 0; nt < NREP; ++nt)
            acc[mt][nt] = floatx4{0.f, 0.f, 0.f, 0.f};

#pragma unroll
    for (int kk = 0; kk < 4; ++kk) {
        half8 af[4];
#pragma unroll
        for (int mt = 0; mt < 4; ++mt) {
            int row = m0 + mt * 16 + lrow;
            if (row >= nrows) row = nrows - 1;  // clamp; stores guarded
            af[mt] = *reinterpret_cast<const half8*>(
                &A[(size_t)row * 128 + kk * 32 + kgrp * 8]);
        }
#pragma unroll
        for (int mt = 0; mt < 4; ++mt)
#pragma unroll
            for (int nt = 0; nt < NREP; ++nt)
                acc[mt][nt] = __builtin_amdgcn_mfma_f32_16x16x32_f16(
                    af[mt], bf[nt][kk], acc[mt][nt], 0, 0, 0);
    }

#pragma unroll
    for (int mt = 0; mt < 4; ++mt) {
#pragma unroll
        for (int r = 0; r < 4; ++r) {
            int row = m0 + mt * 16 + kgrp * 4 + r;
            if (row < nrows) {
                float dn = SCALE_DINV ? dinv[row] : 1.0f;
#pragma unroll
                for (int nt = 0; nt < NREP; ++nt) {
                    float v = acc[mt][nt][r];
                    if (BIAS) v += bv[nt];
                    if (RELU) v = fmaxf(v, 0.0f);
                    if (SCALE_DINV) v *= dn;
                    int col = nbase + nt * 16 + lrow;
                    if (TOUT)
                        out[((size_t)(col >> 3) * nrows + row) * 8 + (col & 7)] =
                            __float2half(v);
                    else
                        out[(size_t)row * OC + col] = __float2half(v);
                }
            }
        }
    }
}

// ---------------------------------------------------------------------------

extern "C" void kernel_launch(void* const* d_in, const int* in_sizes, int n_in,
                              void* d_out, int out_size, void* d_ws, size_t ws_size,
                              hipStream_t stream) {
    const float* x   = (const float*)d_in[0];
    const int*   ei  = (const int*)d_in[1];
    const float* W1  = (const float*)d_in[2];
    const float* b1  = (const float*)d_in[3];
    const float* W2  = (const float*)d_in[4];
    const float* b2  = (const float*)d_in[5];
    float*       out = (float*)d_out;

    const int N = in_sizes[0] / 128;
    const int E = in_sizes[1] / 2;
    const int* srcp = ei;      // edge_index[0]
    const int* dstp = ei + E;  // edge_index[1]

    const int nb = (N + NT - 1) / NT;

    // workspace (512B-aligned), ~84.5 MB:
    //   dinv[N] | cnt[N] | rowptr[N+1] | bsum[nb] | srcs[E]
    //   | regA: xhT[8][N][16] fp16, then h1[N][128] fp16        (25.6 MB)
    //   | regB: aggH[N][128] fp16, then thT[8][N][8] fp16       (25.6 MB)
    //   | regC: outT[8][N][8] fp32                              (25.6 MB)
    char* ws = (char*)d_ws;
    size_t off = 0;
    auto alloc = [&](size_t bytes) {
        char* p = ws + off;
        off = (off + bytes + 511) & ~(size_t)511;
        return p;
    };
    float*  dinv   = (float*)alloc((size_t)N * 4);
    int*    cnt    = (int*)alloc((size_t)N * 4);
    int*    rowptr = (int*)alloc((size_t)(N + 1) * 4);
    int*    bsum   = (int*)alloc((size_t)nb * 4);
    int*    srcs   = (int*)alloc((size_t)E * 4);
    __half* regA   = (__half*)alloc((size_t)N * 128 * 2);
    __half* regB   = (__half*)alloc((size_t)N * 128 * 2);
    float*  regC   = (float*)alloc((size_t)N * 64 * 4);

    // ---- CSR build + norm ----
    zero_counts_k<<<nb, NT, 0, stream>>>(cnt, N);
    deg_count_k<<<(E + NT - 1) / NT, NT, 0, stream>>>(dstp, cnt, E);
    scan1_k<<<nb, NT, 0, stream>>>(cnt, rowptr, bsum, dinv, N);
    scan2_k<<<1, 512, 0, stream>>>(bsum, nb);
    scan3_k<<<(N + 1 + NT - 1) / NT, NT, 0, stream>>>(rowptr, bsum, cnt, N, E);
    {
        const int CH  = 2048;
        const int csz = (E + CH - 1) / CH;
        const int rpx = (N + 7) / 8;
        scatter_xcd_k<<<8 * CH, NT, 0, stream>>>(srcp, dstp, cnt, srcs, E, rpx, csz);
    }

    const int gblocks = ((N + 3) / 4) * 8;  // (node-chunk, slice) grid

    // ---- layer 1: xhT -> aggH -> h1 ----
    conv1T_k<<<(N * 8 + NT - 1) / NT, NT, 0, stream>>>(x, dinv, regA, N);
    gatherT128_k<<<gblocks, NT, 0, stream>>>(
        rowptr, srcs, dinv, (const __half2*)regA, (__half2*)regB, N);
    __half* h1 = regA;  // overlays xhT (dead)
    mgemm_k<128, true, true, false, false><<<(N + 63) / 64, NT, 0, stream>>>(
        regB, W1, b1, nullptr, h1, N);

    // ---- layer 2: thT = (h1 @ W2)*dinv (slice-major) -> outT -> out ----
    __half* thT = regB;  // overlays aggH (dead)
    mgemm_k<64, false, false, true, true><<<(N + 63) / 64, NT, 0, stream>>>(
        h1, W2, nullptr, dinv, thT, N);
    gatherT64_k<<<gblocks, NT, 0, stream>>>(
        rowptr, srcs, dinv, (const __half2*)thT, regC, N);
    tpose_bias_k<<<(N * 32 + NT - 1) / NT, NT, 0, stream>>>(regC, b2, out, N);
}

// Round 9
// 398.903 us; speedup vs baseline: 1.6438x; 1.6438x over previous
//
#include <hip/hip_runtime.h>
#include <hip/hip_fp16.h>

// ---------------------------------------------------------------------------
// 2-layer GCN (PyG GCNConv): deg^{-1/2} sym norm with self-loops.
// Round 9 = round 8 with the slice-stride bug fixed (32 B/node per 16-col
// slice, not 16 B). Structure:
//   - xhT[8][N][16] fp16: 16-col slices, 3.2 MB each -> resident in one XCD L2
//     (blockIdx&7 -> XCD round-robin, validated rounds 5/7 via FETCH drop).
//   - gather wave = 8 nodes x 8 lanes; per 8-edge batch: 1 coalesced srcs
//     load + shfl broadcast + 8 independent 32B data loads (chain depth 2).
//   - aggT slice-major [8][N][16]: gather writes are XCD-local full lines;
//     mgemm1 reads slice-major A (16B fragments never straddle a slice).
//   - gatherT64 writes row-major out directly (+b2): slice = one 64B line.
// ---------------------------------------------------------------------------

#define NT 256

typedef _Float16 half8 __attribute__((ext_vector_type(8)));
typedef float floatx4 __attribute__((ext_vector_type(4)));

// ---------------- CSR build ----------------

__global__ void zero_counts_k(int* __restrict__ c, int n) {
    int i = blockIdx.x * NT + threadIdx.x;
    if (i < n) c[i] = 0;
}

__global__ void deg_count_k(const int* __restrict__ dst, int* __restrict__ c, int e) {
    int i = blockIdx.x * NT + threadIdx.x;
    if (i < e) atomicAdd(&c[dst[i]], 1);
}

// exclusive scan of counts -> rowptr (3-phase); also emits dinv = rsqrt(cnt+1)
__global__ void scan1_k(const int* __restrict__ counts, int* __restrict__ rowptr,
                        int* __restrict__ bsum, float* __restrict__ dinv, int n) {
    __shared__ int s[NT];
    int tid = threadIdx.x, i = blockIdx.x * NT + tid;
    int v = (i < n) ? counts[i] : 0;
    if (i < n) dinv[i] = rsqrtf((float)(v + 1));  // +1 self-loop
    s[tid] = v;
    __syncthreads();
    for (int off = 1; off < NT; off <<= 1) {
        int t = (tid >= off) ? s[tid - off] : 0;
        __syncthreads();
        if (tid >= off) s[tid] += t;
        __syncthreads();
    }
    if (i < n) rowptr[i] = s[tid] - v;  // exclusive within block
    if (tid == NT - 1) bsum[blockIdx.x] = s[tid];
}

__global__ void scan2_k(int* __restrict__ bsum, int nb) {
    __shared__ int s[512];
    __shared__ int carry;
    int tid = threadIdx.x;
    if (tid == 0) carry = 0;
    __syncthreads();
    for (int base = 0; base < nb; base += 512) {
        int i = base + tid;
        int v = (i < nb) ? bsum[i] : 0;
        s[tid] = v;
        __syncthreads();
        for (int off = 1; off < 512; off <<= 1) {
            int t = (tid >= off) ? s[tid - off] : 0;
            __syncthreads();
            if (tid >= off) s[tid] += t;
            __syncthreads();
        }
        int tot = s[511];
        if (i < nb) bsum[i] = s[tid] - v + carry;
        __syncthreads();
        if (tid == 0) carry += tot;
        __syncthreads();
    }
}

__global__ void scan3_k(int* __restrict__ rowptr, const int* __restrict__ bsum,
                        int* __restrict__ cursor, int n, int e) {
    int i = blockIdx.x * NT + threadIdx.x;
    if (i < n) {
        int r = rowptr[i] + bsum[i / NT];
        rowptr[i] = r;
        cursor[i] = r;
    } else if (i == n) {
        rowptr[n] = e;
    }
}

// XCD-localized scatter (round 5): block (blockIdx&7)==q only scatters edges
// whose dst lies in node-region q -> each srcs region written by one XCD.
__global__ __launch_bounds__(NT) void scatter_xcd_k(
    const int* __restrict__ src, const int* __restrict__ dst,
    int* __restrict__ cursor, int* __restrict__ srcs,
    int e, int rpx, int csz) {
    int q  = blockIdx.x & 7;
    int ch = blockIdx.x >> 3;
    int lo = q * rpx, hi = lo + rpx;
    int e0 = ch * csz;
    int e1 = min(e, e0 + csz);
    for (int i = e0 + (int)threadIdx.x; i < e1; i += NT) {
        int d = dst[i];
        if (d >= lo && d < hi) {
            int pos = atomicAdd(&cursor[d], 1);
            srcs[pos] = src[i];
        }
    }
}

// ---------------- conv1T: x (fp32 row-major) -> xhT[8][N][16] fp16 ----------
__global__ void conv1T_k(const float* __restrict__ x, const float* __restrict__ dinv,
                         __half* __restrict__ xhT, int n) {
    int t = blockIdx.x * NT + threadIdx.x;
    int node = t >> 3;
    if (node >= n) return;
    int q = t & 7;
    float dn = dinv[node];
    const float4* xp = reinterpret_cast<const float4*>(x + (size_t)node * 128 + q * 16);
    __half2 h[8];
#pragma unroll
    for (int j = 0; j < 4; ++j) {
        float4 a = xp[j];
        h[2 * j + 0] = __floats2half2_rn(a.x * dn, a.y * dn);
        h[2 * j + 1] = __floats2half2_rn(a.z * dn, a.w * dn);
    }
    int4* op = reinterpret_cast<int4*>(xhT + ((size_t)q * n + node) * 16);
    op[0] = reinterpret_cast<int4*>(h)[0];
    op[1] = reinterpret_cast<int4*>(h)[1];
}

// ---------------- sliced gathers, 8 nodes x 8 lanes per wave ----------------
// Slice layout: [slice][N][16] fp16 -> 32 BYTES per node per slice.

// gatherT128: slice = blockIdx&7 (16 cols). Block = 4 waves = 32 nodes.
// Lane owns one half2 column of one node; group (8 lanes) walks its node's
// edge list with srcs batched 8-at-a-time (coalesced load + shfl broadcast).
// Output aggT slice-major [8][N][16] fp16 (XCD-local full-line writes).
__global__ __launch_bounds__(NT) void gatherT128_k(
    const int* __restrict__ rowptr, const int* __restrict__ srcs,
    const float* __restrict__ dinv, const __half* __restrict__ xhT,
    __half2* __restrict__ aggT, int n, int E) {
    const int slice = blockIdx.x & 7;
    const int chunk = blockIdx.x >> 3;
    const int lane  = threadIdx.x & 63;
    const int wid   = threadIdx.x >> 6;
    const int g     = lane >> 3;   // node sub-group 0..7
    const int c     = lane & 7;    // half2 col within slice / srcs sub-index
    const int node  = chunk * 32 + wid * 8 + g;
    const bool nv   = node < n;

    int e0 = 0, e1 = 0;
    if (nv) { e0 = rowptr[node]; e1 = rowptr[node + 1]; }
    const char* base = (const char*)(xhT + (size_t)slice * n * 16);

    float2 acc = make_float2(0.f, 0.f);
    if (nv)  // self-loop (32 B/node stride)
        acc = __half22float2(*(const __half2*)(base + (size_t)node * 32 + c * 4));

    const int deg = e1 - e0;
    int sidx = 0;
    for (int j = 0; ; ++j) {
        bool act = j < deg;
        if (!__any(act)) break;
        if ((j & 7) == 0) sidx = srcs[min(e0 + j + c, E - 1)];
        int s = __shfl(sidx, (g << 3) | (j & 7), 64);
        if (act) {
            float2 f = __half22float2(
                *(const __half2*)(base + (unsigned)s * 32u + (unsigned)c * 4u));
            acc.x += f.x;
            acc.y += f.y;
        }
    }

    if (nv) {
        float dn = dinv[node];
        aggT[((size_t)slice * n + node) * 8 + c] =
            __floats2half2_rn(acc.x * dn, acc.y * dn);
    }
}

// gatherT64: 4 slices of 16 cols; q8 = blockIdx&7 -> (slice = q8>>1, node-half
// = q8&1), so each slice is L2-resident on 2 XCDs. Writes row-major fp32 out
// directly (+b2): one slice = one 64B line per row -> no cross-XCD sharing.
__global__ __launch_bounds__(NT) void gatherT64_k(
    const int* __restrict__ rowptr, const int* __restrict__ srcs,
    const float* __restrict__ dinv, const __half* __restrict__ thT,
    const float* __restrict__ b2, float* __restrict__ out, int n, int E) {
    const int q8    = blockIdx.x & 7;
    const int slice = q8 >> 1;
    const int chunk = blockIdx.x >> 3;
    const int lane  = threadIdx.x & 63;
    const int wid   = threadIdx.x >> 6;
    const int g     = lane >> 3;
    const int c     = lane & 7;
    const int node  = chunk * 64 + (q8 & 1) * 32 + wid * 8 + g;
    const bool nv   = node < n;

    int e0 = 0, e1 = 0;
    if (nv) { e0 = rowptr[node]; e1 = rowptr[node + 1]; }
    const char* base = (const char*)(thT + (size_t)slice * n * 16);

    float2 acc = make_float2(0.f, 0.f);
    if (nv)  // self-loop (32 B/node stride)
        acc = __half22float2(*(const __half2*)(base + (size_t)node * 32 + c * 4));

    const int deg = e1 - e0;
    int sidx = 0;
    for (int j = 0; ; ++j) {
        bool act = j < deg;
        if (!__any(act)) break;
        if ((j & 7) == 0) sidx = srcs[min(e0 + j + c, E - 1)];
        int s = __shfl(sidx, (g << 3) | (j & 7), 64);
        if (act) {
            float2 f = __half22float2(
                *(const __half2*)(base + (unsigned)s * 32u + (unsigned)c * 4u));
            acc.x += f.x;
            acc.y += f.y;
        }
    }

    if (nv) {
        float dn = dinv[node];
        int col = slice * 16 + c * 2;
        *reinterpret_cast<float2*>(&out[(size_t)node * 64 + col]) =
            make_float2(acc.x * dn + b2[col], acc.y * dn + b2[col + 1]);
    }
}

// ---------------- MFMA fp16 GEMM, register-resident B ----------------
// TIN=true : A is slice-major [8][nrows][16] fp16 (aggT). 16B fragments at
//            k0 in {0,8,...,120} never straddle a 16-col slice.
// TOUT=true: out slice-major [OC/16][nrows][16] fp16 (thT for gatherT64).
template <int OC, bool RELU, bool BIAS, bool SCALE_DINV, bool TIN, bool TOUT>
__global__ __launch_bounds__(NT) void mgemm_k(
    const __half* __restrict__ A, const float* __restrict__ W,
    const float* __restrict__ bias, const float* __restrict__ dinv,
    __half* __restrict__ out, int nrows) {
    constexpr int NREP = OC / 64;  // 2 for OC=128, 1 for OC=64

    const int wid  = threadIdx.x >> 6;
    const int lane = threadIdx.x & 63;
    const int lrow = lane & 15;
    const int kgrp = lane >> 4;
    const int nbase = wid * 16 * NREP;

    // B fragments (loaded once, stay in VGPRs)
    half8 bf[NREP][4];
    float bv[NREP];
#pragma unroll
    for (int nt = 0; nt < NREP; ++nt) {
        int col = nbase + nt * 16 + lrow;
#pragma unroll
        for (int kk = 0; kk < 4; ++kk) {
#pragma unroll
            for (int j = 0; j < 8; ++j) {
                int k = kk * 32 + kgrp * 8 + j;
                bf[nt][kk][j] = (_Float16)W[(size_t)k * OC + col];
            }
        }
        bv[nt] = BIAS ? bias[col] : 0.0f;
    }

    const int m0 = blockIdx.x * 64;

    floatx4 acc[4][NREP];
#pragma unroll
    for (int mt = 0; mt < 4; ++mt)
#pragma unroll
        for (int nt = 0; nt < NREP; ++nt)
            acc[mt][nt] = floatx4{0.f, 0.f, 0.f, 0.f};

#pragma unroll
    for (int kk = 0; kk < 4; ++kk) {
        const int k0 = kk * 32 + kgrp * 8;
        half8 af[4];
#pragma unroll
        for (int mt = 0; mt < 4; ++mt) {
            int row = m0 + mt * 16 + lrow;
            if (row >= nrows) row = nrows - 1;  // clamp; stores guarded
            af[mt] = TIN
                ? *reinterpret_cast<const half8*>(
                      &A[(((size_t)(k0 >> 4)) * nrows + row) * 16 + (k0 & 15)])
                : *reinterpret_cast<const half8*>(&A[(size_t)row * 128 + k0]);
        }
#pragma unroll
        for (int mt = 0; mt < 4; ++mt)
#pragma unroll
            for (int nt = 0; nt < NREP; ++nt)
                acc[mt][nt] = __builtin_amdgcn_mfma_f32_16x16x32_f16(
                    af[mt], bf[nt][kk], acc[mt][nt], 0, 0, 0);
    }

#pragma unroll
    for (int mt = 0; mt < 4; ++mt) {
#pragma unroll
        for (int r = 0; r < 4; ++r) {
            int row = m0 + mt * 16 + kgrp * 4 + r;
            if (row < nrows) {
                float dn = SCALE_DINV ? dinv[row] : 1.0f;
#pragma unroll
                for (int nt = 0; nt < NREP; ++nt) {
                    float v = acc[mt][nt][r];
                    if (BIAS) v += bv[nt];
                    if (RELU) v = fmaxf(v, 0.0f);
                    if (SCALE_DINV) v *= dn;
                    int col = nbase + nt * 16 + lrow;
                    if (TOUT)
                        out[((size_t)(col >> 4) * nrows + row) * 16 + (col & 15)] =
                            __float2half(v);
                    else
                        out[(size_t)row * OC + col] = __float2half(v);
                }
            }
        }
    }
}

// ---------------------------------------------------------------------------

extern "C" void kernel_launch(void* const* d_in, const int* in_sizes, int n_in,
                              void* d_out, int out_size, void* d_ws, size_t ws_size,
                              hipStream_t stream) {
    const float* x   = (const float*)d_in[0];
    const int*   ei  = (const int*)d_in[1];
    const float* W1  = (const float*)d_in[2];
    const float* b1  = (const float*)d_in[3];
    const float* W2  = (const float*)d_in[4];
    const float* b2  = (const float*)d_in[5];
    float*       out = (float*)d_out;

    const int N = in_sizes[0] / 128;
    const int E = in_sizes[1] / 2;
    const int* srcp = ei;      // edge_index[0]
    const int* dstp = ei + E;  // edge_index[1]

    const int nb = (N + NT - 1) / NT;

    // workspace (512B-aligned), ~59 MB:
    //   dinv[N] | cnt[N] | rowptr[N+1] | bsum[nb] | srcs[E]
    //   | regA: xhT[8][N][16] fp16, then h1[N][128] fp16      (25.6 MB)
    //   | regB: aggT[8][N][16] fp16, then thT[4][N][16] fp16  (25.6 MB)
    char* ws = (char*)d_ws;
    size_t off = 0;
    auto alloc = [&](size_t bytes) {
        char* p = ws + off;
        off = (off + bytes + 511) & ~(size_t)511;
        return p;
    };
    float*  dinv   = (float*)alloc((size_t)N * 4);
    int*    cnt    = (int*)alloc((size_t)N * 4);
    int*    rowptr = (int*)alloc((size_t)(N + 1) * 4);
    int*    bsum   = (int*)alloc((size_t)nb * 4);
    int*    srcs   = (int*)alloc((size_t)E * 4);
    __half* regA   = (__half*)alloc((size_t)N * 128 * 2);
    __half* regB   = (__half*)alloc((size_t)N * 128 * 2);

    // ---- CSR build + norm ----
    zero_counts_k<<<nb, NT, 0, stream>>>(cnt, N);
    deg_count_k<<<(E + NT - 1) / NT, NT, 0, stream>>>(dstp, cnt, E);
    scan1_k<<<nb, NT, 0, stream>>>(cnt, rowptr, bsum, dinv, N);
    scan2_k<<<1, 512, 0, stream>>>(bsum, nb);
    scan3_k<<<(N + 1 + NT - 1) / NT, NT, 0, stream>>>(rowptr, bsum, cnt, N, E);
    {
        const int CH  = 2048;
        const int csz = (E + CH - 1) / CH;
        const int rpx = (N + 7) / 8;
        scatter_xcd_k<<<8 * CH, NT, 0, stream>>>(srcp, dstp, cnt, srcs, E, rpx, csz);
    }

    // ---- layer 1: xhT -> aggT (slice-major) -> h1 ----
    conv1T_k<<<(N * 8 + NT - 1) / NT, NT, 0, stream>>>(x, dinv, regA, N);
    gatherT128_k<<<((N + 31) / 32) * 8, NT, 0, stream>>>(
        rowptr, srcs, dinv, regA, (__half2*)regB, N, E);
    __half* h1 = regA;  // overlays xhT (dead)
    mgemm_k<128, true, true, false, true, false><<<(N + 63) / 64, NT, 0, stream>>>(
        regB, W1, b1, nullptr, h1, N);

    // ---- layer 2: thT = (h1 @ W2)*dinv (slice-major) -> out (+b2) ----
    __half* thT = regB;  // overlays aggT (dead)
    mgemm_k<64, false, false, true, false, true><<<(N + 63) / 64, NT, 0, stream>>>(
        h1, W2, nullptr, dinv, thT, N);
    gatherT64_k<<<((N + 63) / 64) * 8, NT, 0, stream>>>(
        rowptr, srcs, dinv, thT, b2, out, N, E);
}

// Round 10
// 352.668 us; speedup vs baseline: 1.8593x; 1.1311x over previous
//
#include <hip/hip_runtime.h>
#include <hip/hip_fp16.h>

// ---------------------------------------------------------------------------
// 2-layer GCN (PyG GCNConv): deg^{-1/2} sym norm with self-loops.
// Round 10: sliced XCD-resident gathers with batched, ballot-free edge loop.
//   - xhT[8][N][16] fp16 slices (3.2 MB -> one XCD L2); blockIdx&7 -> XCD.
//   - gather wave = 8 nodes x 8 lanes. Edge loop runs (wave-max-deg)/8
//     batches: 1 coalesced srcs load (prefetched next batch), 8 shfl
//     broadcasts, 8 UNCONDITIONAL independent 32B loads, masked adds.
//     No per-edge ballot (round-9's latency bug).
//   - aggT slice-major [8][N][16]; mgemm1 reads slice-major A directly.
//   - gatherT64 writes row-major out (+b2): 16-col slice = one 64B line.
// ---------------------------------------------------------------------------

#define NT 256

typedef _Float16 half8 __attribute__((ext_vector_type(8)));
typedef float floatx4 __attribute__((ext_vector_type(4)));

// ---------------- CSR build ----------------

__global__ void zero_counts_k(int* __restrict__ c, int n) {
    int i = blockIdx.x * NT + threadIdx.x;
    if (i < n) c[i] = 0;
}

__global__ void deg_count_k(const int* __restrict__ dst, int* __restrict__ c, int e) {
    int i = blockIdx.x * NT + threadIdx.x;
    if (i < e) atomicAdd(&c[dst[i]], 1);
}

// exclusive scan of counts -> rowptr (3-phase); also emits dinv = rsqrt(cnt+1)
__global__ void scan1_k(const int* __restrict__ counts, int* __restrict__ rowptr,
                        int* __restrict__ bsum, float* __restrict__ dinv, int n) {
    __shared__ int s[NT];
    int tid = threadIdx.x, i = blockIdx.x * NT + tid;
    int v = (i < n) ? counts[i] : 0;
    if (i < n) dinv[i] = rsqrtf((float)(v + 1));  // +1 self-loop
    s[tid] = v;
    __syncthreads();
    for (int off = 1; off < NT; off <<= 1) {
        int t = (tid >= off) ? s[tid - off] : 0;
        __syncthreads();
        if (tid >= off) s[tid] += t;
        __syncthreads();
    }
    if (i < n) rowptr[i] = s[tid] - v;  // exclusive within block
    if (tid == NT - 1) bsum[blockIdx.x] = s[tid];
}

__global__ void scan2_k(int* __restrict__ bsum, int nb) {
    __shared__ int s[512];
    __shared__ int carry;
    int tid = threadIdx.x;
    if (tid == 0) carry = 0;
    __syncthreads();
    for (int base = 0; base < nb; base += 512) {
        int i = base + tid;
        int v = (i < nb) ? bsum[i] : 0;
        s[tid] = v;
        __syncthreads();
        for (int off = 1; off < 512; off <<= 1) {
            int t = (tid >= off) ? s[tid - off] : 0;
            __syncthreads();
            if (tid >= off) s[tid] += t;
            __syncthreads();
        }
        int tot = s[511];
        if (i < nb) bsum[i] = s[tid] - v + carry;
        __syncthreads();
        if (tid == 0) carry += tot;
        __syncthreads();
    }
}

__global__ void scan3_k(int* __restrict__ rowptr, const int* __restrict__ bsum,
                        int* __restrict__ cursor, int n, int e) {
    int i = blockIdx.x * NT + threadIdx.x;
    if (i < n) {
        int r = rowptr[i] + bsum[i / NT];
        rowptr[i] = r;
        cursor[i] = r;
    } else if (i == n) {
        rowptr[n] = e;
    }
}

// XCD-localized scatter (round 5)
__global__ __launch_bounds__(NT) void scatter_xcd_k(
    const int* __restrict__ src, const int* __restrict__ dst,
    int* __restrict__ cursor, int* __restrict__ srcs,
    int e, int rpx, int csz) {
    int q  = blockIdx.x & 7;
    int ch = blockIdx.x >> 3;
    int lo = q * rpx, hi = lo + rpx;
    int e0 = ch * csz;
    int e1 = min(e, e0 + csz);
    for (int i = e0 + (int)threadIdx.x; i < e1; i += NT) {
        int d = dst[i];
        if (d >= lo && d < hi) {
            int pos = atomicAdd(&cursor[d], 1);
            srcs[pos] = src[i];
        }
    }
}

// ---------------- conv1T: x (fp32 row-major) -> xhT[8][N][16] fp16 ----------
__global__ void conv1T_k(const float* __restrict__ x, const float* __restrict__ dinv,
                         __half* __restrict__ xhT, int n) {
    int t = blockIdx.x * NT + threadIdx.x;
    int node = t >> 3;
    if (node >= n) return;
    int q = t & 7;
    float dn = dinv[node];
    const float4* xp = reinterpret_cast<const float4*>(x + (size_t)node * 128 + q * 16);
    __half2 h[8];
#pragma unroll
    for (int j = 0; j < 4; ++j) {
        float4 a = xp[j];
        h[2 * j + 0] = __floats2half2_rn(a.x * dn, a.y * dn);
        h[2 * j + 1] = __floats2half2_rn(a.z * dn, a.w * dn);
    }
    int4* op = reinterpret_cast<int4*>(xhT + ((size_t)q * n + node) * 16);
    op[0] = reinterpret_cast<int4*>(h)[0];
    op[1] = reinterpret_cast<int4*>(h)[1];
}

// ---------------- sliced gathers, 8 nodes x 8 lanes per wave ----------------
// Slice layout: [slice][N][16] fp16 -> 32 BYTES per node per slice.
// Batched edge loop: wave-max-deg batches of 8; srcs prefetched 1 batch
// ahead; 8 unconditional loads per batch (clamped index is always valid).

__global__ __launch_bounds__(NT) void gatherT128_k(
    const int* __restrict__ rowptr, const int* __restrict__ srcs,
    const float* __restrict__ dinv, const __half* __restrict__ xhT,
    __half2* __restrict__ aggT, int n, int E) {
    const int slice = blockIdx.x & 7;
    const int chunk = blockIdx.x >> 3;
    const int lane  = threadIdx.x & 63;
    const int wid   = threadIdx.x >> 6;
    const int g     = lane >> 3;   // node sub-group 0..7
    const int c     = lane & 7;    // half2 col within slice / srcs sub-index
    const int node  = chunk * 32 + wid * 8 + g;
    const bool nv   = node < n;

    int e0 = 0, e1 = 0;
    if (nv) { e0 = rowptr[node]; e1 = rowptr[node + 1]; }
    const char* base = (const char*)(xhT + (size_t)slice * n * 16);

    float2 acc = make_float2(0.f, 0.f);
    if (nv)  // self-loop
        acc = __half22float2(*(const __half2*)(base + (size_t)node * 32 + c * 4));

    const int deg = e1 - e0;
    int md = deg;  // wave-max degree (lanes within a group share deg)
    md = max(md, __shfl_xor(md, 8, 64));
    md = max(md, __shfl_xor(md, 16, 64));
    md = max(md, __shfl_xor(md, 32, 64));

    int sidx = (md > 0) ? srcs[min(e0 + c, E - 1)] : 0;
    for (int jb = 0; jb < md; jb += 8) {
        int snext = (jb + 8 < md) ? srcs[min(e0 + jb + 8 + c, E - 1)] : 0;
#pragma unroll
        for (int u = 0; u < 8; ++u) {
            int s = __shfl(sidx, (g << 3) | u, 64);
            float2 f = __half22float2(
                *(const __half2*)(base + (unsigned)s * 32u + (unsigned)c * 4u));
            if (jb + u < deg) {
                acc.x += f.x;
                acc.y += f.y;
            }
        }
        sidx = snext;
    }

    if (nv) {
        float dn = dinv[node];
        aggT[((size_t)slice * n + node) * 8 + c] =
            __floats2half2_rn(acc.x * dn, acc.y * dn);
    }
}

// gatherT64: 4 slices of 16 cols; q8 -> (slice = q8>>1, node-half = q8&1).
// Writes row-major fp32 out directly (+b2): slice = one 64B line per row.
__global__ __launch_bounds__(NT) void gatherT64_k(
    const int* __restrict__ rowptr, const int* __restrict__ srcs,
    const float* __restrict__ dinv, const __half* __restrict__ thT,
    const float* __restrict__ b2, float* __restrict__ out, int n, int E) {
    const int q8    = blockIdx.x & 7;
    const int slice = q8 >> 1;
    const int chunk = blockIdx.x >> 3;
    const int lane  = threadIdx.x & 63;
    const int wid   = threadIdx.x >> 6;
    const int g     = lane >> 3;
    const int c     = lane & 7;
    const int node  = chunk * 64 + (q8 & 1) * 32 + wid * 8 + g;
    const bool nv   = node < n;

    int e0 = 0, e1 = 0;
    if (nv) { e0 = rowptr[node]; e1 = rowptr[node + 1]; }
    const char* base = (const char*)(thT + (size_t)slice * n * 16);

    float2 acc = make_float2(0.f, 0.f);
    if (nv)  // self-loop
        acc = __half22float2(*(const __half2*)(base + (size_t)node * 32 + c * 4));

    const int deg = e1 - e0;
    int md = deg;
    md = max(md, __shfl_xor(md, 8, 64));
    md = max(md, __shfl_xor(md, 16, 64));
    md = max(md, __shfl_xor(md, 32, 64));

    int sidx = (md > 0) ? srcs[min(e0 + c, E - 1)] : 0;
    for (int jb = 0; jb < md; jb += 8) {
        int snext = (jb + 8 < md) ? srcs[min(e0 + jb + 8 + c, E - 1)] : 0;
#pragma unroll
        for (int u = 0; u < 8; ++u) {
            int s = __shfl(sidx, (g << 3) | u, 64);
            float2 f = __half22float2(
                *(const __half2*)(base + (unsigned)s * 32u + (unsigned)c * 4u));
            if (jb + u < deg) {
                acc.x += f.x;
                acc.y += f.y;
            }
        }
        sidx = snext;
    }

    if (nv) {
        float dn = dinv[node];
        int col = slice * 16 + c * 2;
        *reinterpret_cast<float2*>(&out[(size_t)node * 64 + col]) =
            make_float2(acc.x * dn + b2[col], acc.y * dn + b2[col + 1]);
    }
}

// ---------------- MFMA fp16 GEMM, register-resident B ----------------
// TIN=true : A is slice-major [8][nrows][16] fp16 (aggT).
// TOUT=true: out slice-major [OC/16][nrows][16] fp16 (thT for gatherT64).
template <int OC, bool RELU, bool BIAS, bool SCALE_DINV, bool TIN, bool TOUT>
__global__ __launch_bounds__(NT) void mgemm_k(
    const __half* __restrict__ A, const float* __restrict__ W,
    const float* __restrict__ bias, const float* __restrict__ dinv,
    __half* __restrict__ out, int nrows) {
    constexpr int NREP = OC / 64;  // 2 for OC=128, 1 for OC=64

    const int wid  = threadIdx.x >> 6;
    const int lane = threadIdx.x & 63;
    const int lrow = lane & 15;
    const int kgrp = lane >> 4;
    const int nbase = wid * 16 * NREP;

    // B fragments (loaded once, stay in VGPRs)
    half8 bf[NREP][4];
    float bv[NREP];
#pragma unroll
    for (int nt = 0; nt < NREP; ++nt) {
        int col = nbase + nt * 16 + lrow;
#pragma unroll
        for (int kk = 0; kk < 4; ++kk) {
#pragma unroll
            for (int j = 0; j < 8; ++j) {
                int k = kk * 32 + kgrp * 8 + j;
                bf[nt][kk][j] = (_Float16)W[(size_t)k * OC + col];
            }
        }
        bv[nt] = BIAS ? bias[col] : 0.0f;
    }

    const int m0 = blockIdx.x * 64;

    floatx4 acc[4][NREP];
#pragma unroll
    for (int mt = 0; mt < 4; ++mt)
#pragma unroll
        for (int nt = 0; nt < NREP; ++nt)
            acc[mt][nt] = floatx4{0.f, 0.f, 0.f, 0.f};

#pragma unroll
    for (int kk = 0; kk < 4; ++kk) {
        const int k0 = kk * 32 + kgrp * 8;
        half8 af[4];
#pragma unroll
        for (int mt = 0; mt < 4; ++mt) {
            int row = m0 + mt * 16 + lrow;
            if (row >= nrows) row = nrows - 1;  // clamp; stores guarded
            af[mt] = TIN
                ? *reinterpret_cast<const half8*>(
                      &A[(((size_t)(k0 >> 4)) * nrows + row) * 16 + (k0 & 15)])
                : *reinterpret_cast<const half8*>(&A[(size_t)row * 128 + k0]);
        }
#pragma unroll
        for (int mt = 0; mt < 4; ++mt)
#pragma unroll
            for (int nt = 0; nt < NREP; ++nt)
                acc[mt][nt] = __builtin_amdgcn_mfma_f32_16x16x32_f16(
                    af[mt], bf[nt][kk], acc[mt][nt], 0, 0, 0);
    }

#pragma unroll
    for (int mt = 0; mt < 4; ++mt) {
#pragma unroll
        for (int r = 0; r < 4; ++r) {
            int row = m0 + mt * 16 + kgrp * 4 + r;
            if (row < nrows) {
                float dn = SCALE_DINV ? dinv[row] : 1.0f;
#pragma unroll
                for (int nt = 0; nt < NREP; ++nt) {
                    float v = acc[mt][nt][r];
                    if (BIAS) v += bv[nt];
                    if (RELU) v = fmaxf(v, 0.0f);
                    if (SCALE_DINV) v *= dn;
                    int col = nbase + nt * 16 + lrow;
                    if (TOUT)
                        out[((size_t)(col >> 4) * nrows + row) * 16 + (col & 15)] =
                            __float2half(v);
                    else
                        out[(size_t)row * OC + col] = __float2half(v);
                }
            }
        }
    }
}

// ---------------------------------------------------------------------------

extern "C" void kernel_launch(void* const* d_in, const int* in_sizes, int n_in,
                              void* d_out, int out_size, void* d_ws, size_t ws_size,
                              hipStream_t stream) {
    const float* x   = (const float*)d_in[0];
    const int*   ei  = (const int*)d_in[1];
    const float* W1  = (const float*)d_in[2];
    const float* b1  = (const float*)d_in[3];
    const float* W2  = (const float*)d_in[4];
    const float* b2  = (const float*)d_in[5];
    float*       out = (float*)d_out;

    const int N = in_sizes[0] / 128;
    const int E = in_sizes[1] / 2;
    const int* srcp = ei;      // edge_index[0]
    const int* dstp = ei + E;  // edge_index[1]

    const int nb = (N + NT - 1) / NT;

    // workspace (512B-aligned), ~59 MB:
    //   dinv[N] | cnt[N] | rowptr[N+1] | bsum[nb] | srcs[E]
    //   | regA: xhT[8][N][16] fp16, then h1[N][128] fp16      (25.6 MB)
    //   | regB: aggT[8][N][16] fp16, then thT[4][N][16] fp16  (25.6 MB)
    char* ws = (char*)d_ws;
    size_t off = 0;
    auto alloc = [&](size_t bytes) {
        char* p = ws + off;
        off = (off + bytes + 511) & ~(size_t)511;
        return p;
    };
    float*  dinv   = (float*)alloc((size_t)N * 4);
    int*    cnt    = (int*)alloc((size_t)N * 4);
    int*    rowptr = (int*)alloc((size_t)(N + 1) * 4);
    int*    bsum   = (int*)alloc((size_t)nb * 4);
    int*    srcs   = (int*)alloc((size_t)E * 4);
    __half* regA   = (__half*)alloc((size_t)N * 128 * 2);
    __half* regB   = (__half*)alloc((size_t)N * 128 * 2);

    // ---- CSR build + norm ----
    zero_counts_k<<<nb, NT, 0, stream>>>(cnt, N);
    deg_count_k<<<(E + NT - 1) / NT, NT, 0, stream>>>(dstp, cnt, E);
    scan1_k<<<nb, NT, 0, stream>>>(cnt, rowptr, bsum, dinv, N);
    scan2_k<<<1, 512, 0, stream>>>(bsum, nb);
    scan3_k<<<(N + 1 + NT - 1) / NT, NT, 0, stream>>>(rowptr, bsum, cnt, N, E);
    {
        const int CH  = 2048;
        const int csz = (E + CH - 1) / CH;
        const int rpx = (N + 7) / 8;
        scatter_xcd_k<<<8 * CH, NT, 0, stream>>>(srcp, dstp, cnt, srcs, E, rpx, csz);
    }

    // ---- layer 1: xhT -> aggT (slice-major) -> h1 ----
    conv1T_k<<<(N * 8 + NT - 1) / NT, NT, 0, stream>>>(x, dinv, regA, N);
    gatherT128_k<<<((N + 31) / 32) * 8, NT, 0, stream>>>(
        rowptr, srcs, dinv, regA, (__half2*)regB, N, E);
    __half* h1 = regA;  // overlays xhT (dead)
    mgemm_k<128, true, true, false, true, false><<<(N + 63) / 64, NT, 0, stream>>>(
        regB, W1, b1, nullptr, h1, N);

    // ---- layer 2: thT = (h1 @ W2)*dinv (slice-major) -> out (+b2) ----
    __half* thT = regB;  // overlays aggT (dead)
    mgemm_k<64, false, false, true, false, true><<<(N + 63) / 64, NT, 0, stream>>>(
        h1, W2, nullptr, dinv, thT, N);
    gatherT64_k<<<((N + 63) / 64) * 8, NT, 0, stream>>>(
        rowptr, srcs, dinv, thT, b2, out, N, E);
}

// Round 11
// 326.430 us; speedup vs baseline: 2.0088x; 1.0804x over previous
//
#include <hip/hip_runtime.h>
#include <hip/hip_fp16.h>

// ---------------------------------------------------------------------------
// 2-layer GCN (PyG GCNConv): deg^{-1/2} sym norm with self-loops.
// Round 11: sliced XCD-resident gathers, instruction-dieted inner loop.
//   - Dummy-padded CSR: each node's src list padded to x8 with dummy index N
//     pointing at a zeroed payload row -> NO masking, NO ballots in the loop.
//   - v_dot2_f32_f16 (fdot2) accumulate: 2 VALU per half2 (fp32-exact).
//   - 32-bit offset addressing: v_lshl_add_u32 + saddr load (1 VALU/load).
//   - xhT[8][N+1][16] fp16 slices (3.2 MB -> one XCD L2, blockIdx&7 -> XCD).
//   - aggT slice-major [8][N][16]; mgemm1 reads it directly (TIN).
//   - thT [4][N+1][16]; gatherT64 writes row-major out (+b2) directly.
// ---------------------------------------------------------------------------

#define NT 256

typedef _Float16 half8 __attribute__((ext_vector_type(8)));
typedef _Float16 h2 __attribute__((ext_vector_type(2)));
typedef float floatx4 __attribute__((ext_vector_type(4)));

#if __has_builtin(__builtin_amdgcn_fdot2)
__device__ __forceinline__ float dot2f(h2 a, h2 b, float c) {
    return __builtin_amdgcn_fdot2(a, b, c, false);
}
#else
__device__ __forceinline__ float dot2f(h2 a, h2 b, float c) {
    return c + (float)a.x * (float)b.x + (float)a.y * (float)b.y;
}
#endif

// ---------------- CSR build ----------------

__global__ void zero_counts_k(int* __restrict__ c, int n) {
    int i = blockIdx.x * NT + threadIdx.x;
    if (i < n) c[i] = 0;
}

__global__ void deg_count_k(const int* __restrict__ dst, int* __restrict__ c, int e) {
    int i = blockIdx.x * NT + threadIdx.x;
    if (i < e) atomicAdd(&c[dst[i]], 1);
}

// fill srcs with dummy index (padding holes resolve to the zero row)
__global__ void fill_k(int* __restrict__ srcs, int val, int m) {
    int i = blockIdx.x * NT + threadIdx.x;
    if (i < m) srcs[i] = val;
}

// exclusive scan of PADDED counts -> rowptr; emits dinv = rsqrt(cnt+1) and
// pdeg[i] = (cnt+7)&~7 (padded degree).
__global__ void scan1_k(const int* __restrict__ counts, int* __restrict__ rowptr,
                        int* __restrict__ bsum, float* __restrict__ dinv,
                        int* __restrict__ pdeg, int n) {
    __shared__ int s[NT];
    int tid = threadIdx.x, i = blockIdx.x * NT + tid;
    int v = (i < n) ? counts[i] : 0;
    int pv = (v + 7) & ~7;
    if (i < n) {
        dinv[i] = rsqrtf((float)(v + 1));  // +1 self-loop
        pdeg[i] = pv;
    }
    s[tid] = pv;
    __syncthreads();
    for (int off = 1; off < NT; off <<= 1) {
        int t = (tid >= off) ? s[tid - off] : 0;
        __syncthreads();
        if (tid >= off) s[tid] += t;
        __syncthreads();
    }
    if (i < n) rowptr[i] = s[tid] - pv;  // exclusive within block
    if (tid == NT - 1) bsum[blockIdx.x] = s[tid];
}

__global__ void scan2_k(int* __restrict__ bsum, int nb) {
    __shared__ int s[512];
    __shared__ int carry;
    int tid = threadIdx.x;
    if (tid == 0) carry = 0;
    __syncthreads();
    for (int base = 0; base < nb; base += 512) {
        int i = base + tid;
        int v = (i < nb) ? bsum[i] : 0;
        s[tid] = v;
        __syncthreads();
        for (int off = 1; off < 512; off <<= 1) {
            int t = (tid >= off) ? s[tid - off] : 0;
            __syncthreads();
            if (tid >= off) s[tid] += t;
            __syncthreads();
        }
        int tot = s[511];
        if (i < nb) bsum[i] = s[tid] - v + carry;
        __syncthreads();
        if (tid == 0) carry += tot;
        __syncthreads();
    }
}

__global__ void scan3_k(int* __restrict__ rowptr, const int* __restrict__ bsum,
                        int* __restrict__ cursor, int n) {
    int i = blockIdx.x * NT + threadIdx.x;
    if (i < n) {
        int r = rowptr[i] + bsum[i / NT];
        rowptr[i] = r;
        cursor[i] = r;
    }
}

// XCD-localized scatter (round 5): block (blockIdx&7)==q only scatters edges
// whose dst lies in node-region q -> each srcs region written by one XCD.
__global__ __launch_bounds__(NT) void scatter_xcd_k(
    const int* __restrict__ src, const int* __restrict__ dst,
    int* __restrict__ cursor, int* __restrict__ srcs,
    int e, int rpx, int csz) {
    int q  = blockIdx.x & 7;
    int ch = blockIdx.x >> 3;
    int lo = q * rpx, hi = lo + rpx;
    int e0 = ch * csz;
    int e1 = min(e, e0 + csz);
    for (int i = e0 + (int)threadIdx.x; i < e1; i += NT) {
        int d = dst[i];
        if (d >= lo && d < hi) {
            int pos = atomicAdd(&cursor[d], 1);
            srcs[pos] = src[i];
        }
    }
}

// ---------------- conv1T: x -> xhT[8][N+1][16] fp16 (row N zeroed) ---------
__global__ void conv1T_k(const float* __restrict__ x, const float* __restrict__ dinv,
                         __half* __restrict__ xhT, int n) {
    int t = blockIdx.x * NT + threadIdx.x;
    int node = t >> 3;
    if (node > n) return;
    int q = t & 7;
    int4 o0, o1;
    if (node == n) {
        o0 = make_int4(0, 0, 0, 0);
        o1 = o0;
    } else {
        float dn = dinv[node];
        const float4* xp =
            reinterpret_cast<const float4*>(x + (size_t)node * 128 + q * 16);
        __half2 h[8];
#pragma unroll
        for (int j = 0; j < 4; ++j) {
            float4 a = xp[j];
            h[2 * j + 0] = __floats2half2_rn(a.x * dn, a.y * dn);
            h[2 * j + 1] = __floats2half2_rn(a.z * dn, a.w * dn);
        }
        o0 = reinterpret_cast<int4*>(h)[0];
        o1 = reinterpret_cast<int4*>(h)[1];
    }
    int4* op = reinterpret_cast<int4*>(xhT + ((size_t)q * (n + 1) + node) * 16);
    op[0] = o0;
    op[1] = o1;
}

// zero thT's dummy rows (4 slices x 16 halves); run after mgemm1, before mgemm2
__global__ void zero_thT_k(__half* __restrict__ thT, int n) {
    int t = threadIdx.x;  // 64 threads
    int sl = t >> 4, j = t & 15;
    thT[((size_t)sl * (n + 1) + n) * 16 + j] = __float2half(0.0f);
}

// ---------------- sliced gathers, 8 nodes x 8 lanes per wave ----------------
// Payload: [slice][N+1][16] fp16 -> 32 B per node per slice; row N is zeros.
// Per batch of 8 edges: 1 coalesced srcs load (next batch prefetched
// unconditionally into the padded buffer), 8 shfl broadcasts, 8 unconditional
// 4B loads, 16 fdot2 fp32-accumulates. No masks, no ballots.

__global__ __launch_bounds__(NT) void gatherT128_k(
    const int* __restrict__ rowptr, const int* __restrict__ pdeg,
    const int* __restrict__ srcs, const float* __restrict__ dinv,
    const __half* __restrict__ xhT, __half2* __restrict__ aggT, int n) {
    const int slice = blockIdx.x & 7;
    const int chunk = blockIdx.x >> 3;
    const int lane  = threadIdx.x & 63;
    const int wid   = threadIdx.x >> 6;
    const int g     = lane >> 3;   // node sub-group 0..7
    const int c     = lane & 7;    // half2 col within slice / srcs sub-index
    const int node  = chunk * 32 + wid * 8 + g;
    if (node >= n) return;  // shfl sources stay within each 8-lane group

    const int e0 = rowptr[node];
    const int pd = pdeg[node];
    const char* base = (const char*)(xhT + (size_t)slice * (n + 1) * 16);
    const unsigned c4 = (unsigned)c * 4u;
    const h2 b10 = {(_Float16)1.0f, (_Float16)0.0f};
    const h2 b01 = {(_Float16)0.0f, (_Float16)1.0f};

    // self-loop
    h2 fs = *(const h2*)(base + (size_t)node * 32 + c4);
    float ax = dot2f(fs, b10, 0.0f);
    float ay = dot2f(fs, b01, 0.0f);

    int sidx = srcs[e0 + c];
    for (int jb = 0; jb < pd; jb += 8) {
        int snext = srcs[e0 + jb + 8 + c];  // unconditional: buffer padded
#pragma unroll
        for (int u = 0; u < 8; ++u) {
            int s = __shfl(sidx, (g << 3) | u, 64);
            h2 f = *(const h2*)(base + (unsigned)s * 32u + c4);
            ax = dot2f(f, b10, ax);
            ay = dot2f(f, b01, ay);
        }
        sidx = snext;
    }

    float dn = dinv[node];
    aggT[((size_t)slice * n + node) * 8 + c] = __floats2half2_rn(ax * dn, ay * dn);
}

// gatherT64: 4 slices of 16 cols; q8 -> (slice = q8>>1, node-half = q8&1).
// Writes row-major fp32 out directly (+b2): slice = one 64B line per row.
__global__ __launch_bounds__(NT) void gatherT64_k(
    const int* __restrict__ rowptr, const int* __restrict__ pdeg,
    const int* __restrict__ srcs, const float* __restrict__ dinv,
    const __half* __restrict__ thT, const float* __restrict__ b2,
    float* __restrict__ out, int n) {
    const int q8    = blockIdx.x & 7;
    const int slice = q8 >> 1;
    const int chunk = blockIdx.x >> 3;
    const int lane  = threadIdx.x & 63;
    const int wid   = threadIdx.x >> 6;
    const int g     = lane >> 3;
    const int c     = lane & 7;
    const int node  = chunk * 64 + (q8 & 1) * 32 + wid * 8 + g;
    if (node >= n) return;

    const int e0 = rowptr[node];
    const int pd = pdeg[node];
    const char* base = (const char*)(thT + (size_t)slice * (n + 1) * 16);
    const unsigned c4 = (unsigned)c * 4u;
    const h2 b10 = {(_Float16)1.0f, (_Float16)0.0f};
    const h2 b01 = {(_Float16)0.0f, (_Float16)1.0f};

    h2 fs = *(const h2*)(base + (size_t)node * 32 + c4);
    float ax = dot2f(fs, b10, 0.0f);
    float ay = dot2f(fs, b01, 0.0f);

    int sidx = srcs[e0 + c];
    for (int jb = 0; jb < pd; jb += 8) {
        int snext = srcs[e0 + jb + 8 + c];
#pragma unroll
        for (int u = 0; u < 8; ++u) {
            int s = __shfl(sidx, (g << 3) | u, 64);
            h2 f = *(const h2*)(base + (unsigned)s * 32u + c4);
            ax = dot2f(f, b10, ax);
            ay = dot2f(f, b01, ay);
        }
        sidx = snext;
    }

    float dn = dinv[node];
    int col = slice * 16 + c * 2;
    *reinterpret_cast<float2*>(&out[(size_t)node * 64 + col]) =
        make_float2(ax * dn + b2[col], ay * dn + b2[col + 1]);
}

// ---------------- MFMA fp16 GEMM, register-resident B ----------------
// TIN=true : A is slice-major [8][nrows][16] fp16 (aggT, stride nrows).
// TOUT=true: out slice-major [OC/16][orows][16] fp16 (thT, stride orows).
template <int OC, bool RELU, bool BIAS, bool SCALE_DINV, bool TIN, bool TOUT>
__global__ __launch_bounds__(NT) void mgemm_k(
    const __half* __restrict__ A, const float* __restrict__ W,
    const float* __restrict__ bias, const float* __restrict__ dinv,
    __half* __restrict__ out, int nrows, int orows) {
    constexpr int NREP = OC / 64;  // 2 for OC=128, 1 for OC=64

    const int wid  = threadIdx.x >> 6;
    const int lane = threadIdx.x & 63;
    const int lrow = lane & 15;
    const int kgrp = lane >> 4;
    const int nbase = wid * 16 * NREP;

    // B fragments (loaded once, stay in VGPRs)
    half8 bf[NREP][4];
    float bv[NREP];
#pragma unroll
    for (int nt = 0; nt < NREP; ++nt) {
        int col = nbase + nt * 16 + lrow;
#pragma unroll
        for (int kk = 0; kk < 4; ++kk) {
#pragma unroll
            for (int j = 0; j < 8; ++j) {
                int k = kk * 32 + kgrp * 8 + j;
                bf[nt][kk][j] = (_Float16)W[(size_t)k * OC + col];
            }
        }
        bv[nt] = BIAS ? bias[col] : 0.0f;
    }

    const int m0 = blockIdx.x * 64;

    floatx4 acc[4][NREP];
#pragma unroll
    for (int mt = 0; mt < 4; ++mt)
#pragma unroll
        for (int nt = 0; nt < NREP; ++nt)
            acc[mt][nt] = floatx4{0.f, 0.f, 0.f, 0.f};

#pragma unroll
    for (int kk = 0; kk < 4; ++kk) {
        const int k0 = kk * 32 + kgrp * 8;
        half8 af[4];
#pragma unroll
        for (int mt = 0; mt < 4; ++mt) {
            int row = m0 + mt * 16 + lrow;
            if (row >= nrows) row = nrows - 1;  // clamp; stores guarded
            af[mt] = TIN
                ? *reinterpret_cast<const half8*>(
                      &A[(((size_t)(k0 >> 4)) * nrows + row) * 16 + (k0 & 15)])
                : *reinterpret_cast<const half8*>(&A[(size_t)row * 128 + k0]);
        }
#pragma unroll
        for (int mt = 0; mt < 4; ++mt)
#pragma unroll
            for (int nt = 0; nt < NREP; ++nt)
                acc[mt][nt] = __builtin_amdgcn_mfma_f32_16x16x32_f16(
                    af[mt], bf[nt][kk], acc[mt][nt], 0, 0, 0);
    }

#pragma unroll
    for (int mt = 0; mt < 4; ++mt) {
#pragma unroll
        for (int r = 0; r < 4; ++r) {
            int row = m0 + mt * 16 + kgrp * 4 + r;
            if (row < nrows) {
                float dn = SCALE_DINV ? dinv[row] : 1.0f;
#pragma unroll
                for (int nt = 0; nt < NREP; ++nt) {
                    float v = acc[mt][nt][r];
                    if (BIAS) v += bv[nt];
                    if (RELU) v = fmaxf(v, 0.0f);
                    if (SCALE_DINV) v *= dn;
                    int col = nbase + nt * 16 + lrow;
                    if (TOUT)
                        out[((size_t)(col >> 4) * orows + row) * 16 + (col & 15)] =
                            __float2half(v);
                    else
                        out[(size_t)row * OC + col] = __float2half(v);
                }
            }
        }
    }
}

// ---------------------------------------------------------------------------

extern "C" void kernel_launch(void* const* d_in, const int* in_sizes, int n_in,
                              void* d_out, int out_size, void* d_ws, size_t ws_size,
                              hipStream_t stream) {
    const float* x   = (const float*)d_in[0];
    const int*   ei  = (const int*)d_in[1];
    const float* W1  = (const float*)d_in[2];
    const float* b1  = (const float*)d_in[3];
    const float* W2  = (const float*)d_in[4];
    const float* b2  = (const float*)d_in[5];
    float*       out = (float*)d_out;

    const int N = in_sizes[0] / 128;
    const int E = in_sizes[1] / 2;
    const int* srcp = ei;      // edge_index[0]
    const int* dstp = ei + E;  // edge_index[1]

    const int nb   = (N + NT - 1) / NT;
    const int EPAD = E + 8 * N;  // >= sum(padded degrees) + prefetch slack

    // workspace (512B-aligned), ~62.5 MB:
    //   dinv[N] | cnt[N] | pdeg[N] | rowptr[N] | bsum[nb] | srcs[EPAD]
    //   | regA: xhT[8][N+1][16] fp16, then h1[N][128] fp16
    //   | regB: aggT[8][N][16] fp16, then thT[4][N+1][16] fp16
    char* ws = (char*)d_ws;
    size_t off = 0;
    auto alloc = [&](size_t bytes) {
        char* p = ws + off;
        off = (off + bytes + 511) & ~(size_t)511;
        return p;
    };
    float*  dinv   = (float*)alloc((size_t)N * 4);
    int*    cnt    = (int*)alloc((size_t)N * 4);   // counts, then scatter cursor
    int*    pdeg   = (int*)alloc((size_t)N * 4);
    int*    rowptr = (int*)alloc((size_t)N * 4);
    int*    bsum   = (int*)alloc((size_t)nb * 4);
    int*    srcs   = (int*)alloc((size_t)EPAD * 4);
    __half* regA   = (__half*)alloc((size_t)(N + 1) * 128 * 2);
    __half* regB   = (__half*)alloc((size_t)(N + 1) * 128 * 2);

    // ---- padded CSR build + norm ----
    zero_counts_k<<<nb, NT, 0, stream>>>(cnt, N);
    deg_count_k<<<(E + NT - 1) / NT, NT, 0, stream>>>(dstp, cnt, E);
    fill_k<<<(EPAD + NT - 1) / NT, NT, 0, stream>>>(srcs, N, EPAD);  // dummy = N
    scan1_k<<<nb, NT, 0, stream>>>(cnt, rowptr, bsum, dinv, pdeg, N);
    scan2_k<<<1, 512, 0, stream>>>(bsum, nb);
    scan3_k<<<nb, NT, 0, stream>>>(rowptr, bsum, cnt, N);
    {
        const int CH  = 2048;
        const int csz = (E + CH - 1) / CH;
        const int rpx = (N + 7) / 8;
        scatter_xcd_k<<<8 * CH, NT, 0, stream>>>(srcp, dstp, cnt, srcs, E, rpx, csz);
    }

    // ---- layer 1: xhT (padded, dummy row zeroed) -> aggT -> h1 ----
    conv1T_k<<<((N + 1) * 8 + NT - 1) / NT, NT, 0, stream>>>(x, dinv, regA, N);
    gatherT128_k<<<((N + 31) / 32) * 8, NT, 0, stream>>>(
        rowptr, pdeg, srcs, dinv, regA, (__half2*)regB, N);
    __half* h1 = regA;  // overlays xhT (dead)
    mgemm_k<128, true, true, false, true, false><<<(N + 63) / 64, NT, 0, stream>>>(
        regB, W1, b1, nullptr, h1, N, N);

    // ---- layer 2: thT = (h1 @ W2)*dinv (slice-major, padded) -> out ----
    __half* thT = regB;  // overlays aggT (dead)
    zero_thT_k<<<1, 64, 0, stream>>>(thT, N);
    mgemm_k<64, false, false, true, false, true><<<(N + 63) / 64, NT, 0, stream>>>(
        h1, W2, nullptr, dinv, thT, N, N + 1);
    gatherT64_k<<<((N + 63) / 64) * 8, NT, 0, stream>>>(
        rowptr, pdeg, srcs, dinv, thT, b2, out, N);
}